// Round 1
// 169.387 us; speedup vs baseline: 1.0140x; 1.0140x over previous
//
#include <hip/hip_runtime.h>
#include <hip/hip_bf16.h>

#define N_NODES 100000
#define N_EDGES 1600000
#define NT_TILES 1563          // ceil(N_NODES/64)
#define PRE_BLKX 384           // 384*2 = 768 blocks = EXACTLY 3 blocks/CU
                               // residency (52.2 KB LDS) -> no serial 2nd
                               // round (R8/R9's 784 blocks had a 16-block
                               // tail ~= a full extra round)

// ws layout: Aq @0 (12.8 MB) | Bq @12.8M (12.8 MB) | sA @25.6M | sB @26.0M
#define BQ_OFF 12800000
#define SA_OFF 25600000
#define SB_OFF 26000000

typedef __attribute__((ext_vector_type(8))) short short8v;   // 8 bf16 = 4 VGPRs
typedef __attribute__((ext_vector_type(4))) float float4v;   // MFMA C/D

// ---------- bf16 helpers ----------
__device__ __forceinline__ unsigned short f2bf(float f) {
    unsigned int u = __float_as_uint(f);
    u += 0x7fffu + ((u >> 16) & 1u);   // round-to-nearest-even
    return (unsigned short)(u >> 16);
}
__device__ __forceinline__ unsigned int pack2bf(float a, float b) {
    return (unsigned int)f2bf(a) | ((unsigned int)f2bf(b) << 16);
}
__device__ __forceinline__ float2 bfpair(unsigned int w) {
    return float2{__uint_as_float(w << 16), __uint_as_float(w & 0xffff0000u)};
}
// magic-add quantize: biased uint8 (round(f*inv)+128) in the LOW BYTE, RNE.
#define MAGICB 12583040.0f     // 2^23 + 2^22 + 128
__device__ __forceinline__ unsigned int qmagic(float f, float inv) {
    return __float_as_uint(fmaf(f, inv, MAGICB));
}

// ---------------------------------------------------------------------------
// Phase 1 (MFMA, persistent node-loop) + biased-uint8 row quantization:
//   by==0: Aq[n][c] = q128(x[n]@W1[c,:128] + b1[c]),  sA[n] = rowmax/127
//   by==1: Bq[n][c] = q128(x[n]@W1[c,128:]),          sB[n] = rowmax/127
// R11 measured-best structure (W staged once/block in LDS, 4-tile node loop,
// x prefetch in regs, LDS-staged quant epilogue, grid 384x2 -> no residency
// tail). Beats all four attempted restructures (R10/R12/R13). LDS strides
// 136/132: 2-way bank aliasing on hot b128 reads = free (m136).
// 52.2 KB -> 3 blocks/CU.   [UNCHANGED this round]
// ---------------------------------------------------------------------------
__global__ __launch_bounds__(256) void precompute_kernel(
    const float* __restrict__ x, const float* __restrict__ W1,
    const float* __restrict__ b1, unsigned char* __restrict__ Aq,
    unsigned char* __restrict__ Bq, float* __restrict__ sA,
    float* __restrict__ sB) {
    __shared__ unsigned short wlds[128 * 136];
    __shared__ unsigned short xlds[64 * 136];   // input tile AND acc staging

    const int tid = threadIdx.x;
    const int by = blockIdx.y;            // 0: A-half (+b1), 1: B-half
    unsigned char* __restrict__ Q = by ? Bq : Aq;
    float* __restrict__ S = by ? sB : sA;

    const int wave = tid >> 6;
    const int lane = tid & 63;
    const int quad = lane >> 4;
    const int l15 = lane & 15;

    float4 b1v[2];
#pragma unroll
    for (int j = 0; j < 2; ++j)
        b1v[j] = *reinterpret_cast<const float4*>(b1 + wave * 32 + j * 16 + quad * 4);

    // ---- stage W half ONCE: W1[jl][by*128 + 0..127] -> bf16
#pragma unroll
    for (int i = 0; i < 16; ++i) {
        int fi = tid + i * 256;
        int jl = fi >> 5, c4 = fi & 31;
        float4 w4 = reinterpret_cast<const float4*>(W1)[(size_t)jl * 64 + by * 32 + c4];
        unsigned int* d = reinterpret_cast<unsigned int*>(&wlds[jl * 136 + c4 * 4]);
        d[0] = pack2bf(w4.x, w4.y);
        d[1] = pack2bf(w4.z, w4.w);
    }

    // ---- prologue: first tile's x into regs
    float4 xr[8];
    int t = blockIdx.x;
#pragma unroll
    for (int i = 0; i < 8; ++i) {
        int fi = tid + i * 256;
        int n = fi >> 5, c4 = fi & 31;
        int nn = t * 64 + n; nn = nn < N_NODES ? nn : N_NODES - 1;
        xr[i] = reinterpret_cast<const float4*>(x)[(size_t)nn * 32 + c4];
    }

    for (; t < NT_TILES; t += PRE_BLKX) {
        __syncthreads();   // prev epilogue's LDS reads done (covers W too)
#pragma unroll
        for (int i = 0; i < 8; ++i) {
            int fi = tid + i * 256;
            int n = fi >> 5, c4 = fi & 31;
            unsigned int* d = reinterpret_cast<unsigned int*>(&xlds[n * 136 + c4 * 4]);
            d[0] = pack2bf(xr[i].x, xr[i].y);
            d[1] = pack2bf(xr[i].z, xr[i].w);
        }
        __syncthreads();

        const int tn = t + PRE_BLKX;
        if (tn < NT_TILES) {
#pragma unroll
            for (int i = 0; i < 8; ++i) {
                int fi = tid + i * 256;
                int n = fi >> 5, c4 = fi & 31;
                int nn = tn * 64 + n; nn = nn < N_NODES ? nn : N_NODES - 1;
                xr[i] = reinterpret_cast<const float4*>(x)[(size_t)nn * 32 + c4];
            }
        }

        float4v acc[4][2];
#pragma unroll
        for (int i = 0; i < 4; ++i)
#pragma unroll
            for (int j = 0; j < 2; ++j) acc[i][j] = float4v{0.f, 0.f, 0.f, 0.f};

#pragma unroll
        for (int s = 0; s < 4; ++s) {
            const int k0 = s * 32 + quad * 8;
            short8v wf[2], xf[4];
#pragma unroll
            for (int j = 0; j < 2; ++j)
                wf[j] = *reinterpret_cast<const short8v*>(&wlds[(wave * 32 + j * 16 + l15) * 136 + k0]);
#pragma unroll
            for (int i = 0; i < 4; ++i)
                xf[i] = *reinterpret_cast<const short8v*>(&xlds[(i * 16 + l15) * 136 + k0]);
#pragma unroll
            for (int i = 0; i < 4; ++i)
#pragma unroll
                for (int j = 0; j < 2; ++j)
                    acc[i][j] = __builtin_amdgcn_mfma_f32_16x16x32_bf16(wf[j], xf[i], acc[i][j], 0, 0, 0);
        }
        __syncthreads();   // all xlds input reads done -> reuse as staging

        // ---- acc (+b1) -> LDS staging, bf16, stride 132 shorts
#pragma unroll
        for (int i = 0; i < 4; ++i) {
            const int nl = i * 16 + l15;
#pragma unroll
            for (int j = 0; j < 2; ++j) {
                const int colb = wave * 32 + j * 16 + quad * 4;
                float r0 = acc[i][j][0], r1 = acc[i][j][1];
                float r2 = acc[i][j][2], r3 = acc[i][j][3];
                if (by == 0) {
                    r0 += b1v[j].x; r1 += b1v[j].y;
                    r2 += b1v[j].z; r3 += b1v[j].w;
                }
                uint2 st = {pack2bf(r0, r1), pack2bf(r2, r3)};
                *reinterpret_cast<uint2*>(&xlds[nl * 132 + colb]) = st;
            }
        }
        __syncthreads();

        // ---- per-row max + magic quantize; thread = (row = tid>>2, part = tid&3)
        const int row = tid >> 2, part = tid & 3;
        const int n = t * 64 + row;
        uint4 wv[4];
#pragma unroll
        for (int q = 0; q < 4; ++q)
            wv[q] = *reinterpret_cast<const uint4*>(&xlds[row * 132 + part * 32 + q * 8]);

        float m = 1e-6f;
#pragma unroll
        for (int q = 0; q < 4; ++q) {
            unsigned int ws[4] = {wv[q].x, wv[q].y, wv[q].z, wv[q].w};
#pragma unroll
            for (int w = 0; w < 4; ++w) {
                float2 f = bfpair(ws[w]);
                m = fmaxf(m, fmaxf(fabsf(f.x), fabsf(f.y)));
            }
        }
        m = fmaxf(m, __shfl_xor(m, 1));   // quad (4 parts of one row) reduce
        m = fmaxf(m, __shfl_xor(m, 2));
        const float inv = 127.0f / m;

        unsigned int ob[8];
#pragma unroll
        for (int q = 0; q < 4; ++q) {
            unsigned int ws[4] = {wv[q].x, wv[q].y, wv[q].z, wv[q].w};
#pragma unroll
            for (int w = 0; w < 2; ++w) {
                float2 f0 = bfpair(ws[2 * w + 0]);
                float2 f1 = bfpair(ws[2 * w + 1]);
                unsigned int q0 = qmagic(f0.x, inv), q1 = qmagic(f0.y, inv);
                unsigned int q2 = qmagic(f1.x, inv), q3 = qmagic(f1.y, inv);
                ob[q * 2 + w] = (q0 & 0xffu) | ((q1 & 0xffu) << 8) |
                                ((q2 & 0xffu) << 16) | (q3 << 24);
            }
        }
        if (n < N_NODES) {
            uint4 s0 = {ob[0], ob[1], ob[2], ob[3]};
            uint4 s1 = {ob[4], ob[5], ob[6], ob[7]};
            uint4* dst = reinterpret_cast<uint4*>(Q + (size_t)n * 128 + part * 32);
            dst[0] = s0;
            dst[1] = s1;
            if (part == 0) S[n] = m * (1.0f / 127.0f);
        }
    }
}

// ---------------------------------------------------------------------------
// Phase 2: out[e] = W2 . relu(dq(Aq[u]) + dq(Bq[v])) + b2
// Biased uint8: relu(A+B) = su * max(fma(ub, r, ua) - c, 0), r = sv/su,
// c = 128(1+r); su applied once after the 4-lane reduction.
//
// R14 changes (this round):
//  * LINE-COALESCED feature map: lane sl covers [16sl,16sl+16) u
//    [64+16sl,64+16sl+16), so each dwordx4 gather instruction covers ONE
//    contiguous 64B line across an edge's 4 lanes. Old map (stride-32)
//    touched BOTH lines per instruction -> 2x duplicate line-requests
//    through TA/L2 (128 vs 64 unique per wave-iter).
//  * 2x edge unroll: all 8 row gathers + 4 scale loads of an edge PAIR
//    issued before either compute block -> 2x outstanding VMEM, compute of
//    half 0 overlaps in-flight loads of half 1 (counted-vmcnt slack instead
//    of per-16-edge full drain).
// FETCH_SIZE predicted unchanged (~189 MB unique-line floor); dur drops iff
// the kernel was issue/latency-bound, stays iff L3 service-rate-bound.
// __launch_bounds__(256,4): R8/R10-verified — (256,8) raised WRITE_SIZE
// 6.4->21 MB via partial-line out writebacks (R9 regression).
// ---------------------------------------------------------------------------
template <bool IS64>
__device__ __forceinline__ void edge_loop(
    const long long* __restrict__ ei, const unsigned char* __restrict__ Aq,
    const unsigned char* __restrict__ Bq, const float* __restrict__ sA,
    const float* __restrict__ sB, const float* __restrict__ W2, float bias2,
    float* __restrict__ out, int wid, int nwaves, int eg, int sl) {
    const int k0a = sl * 16;             // line-0 chunk for this lane
    const int k0b = 64 + sl * 16;        // line-1 chunk for this lane
    float w2f[32];
#pragma unroll
    for (int j = 0; j < 4; ++j)
        *reinterpret_cast<float4*>(&w2f[j * 4]) =
            *reinterpret_cast<const float4*>(W2 + k0a + j * 4);
#pragma unroll
    for (int j = 0; j < 4; ++j)
        *reinterpret_cast<float4*>(&w2f[16 + j * 4]) =
            *reinterpret_cast<const float4*>(W2 + k0b + j * 4);
    const int* e32 = reinterpret_cast<const int*>(ei);

    for (int base = wid * 32; base < N_EDGES; base += nwaves * 32) {
        const int e0 = base + eg;          // N_EDGES % 32 == 0 -> both in range
        const int e1 = base + 16 + eg;
        int u0, v0, u1, v1;
        if (IS64) {
            u0 = (int)ei[e0]; v0 = (int)ei[N_EDGES + e0];
            u1 = (int)ei[e1]; v1 = (int)ei[N_EDGES + e1];
        } else {
            u0 = e32[e0]; v0 = e32[N_EDGES + e0];
            u1 = e32[e1]; v1 = e32[N_EDGES + e1];
        }
        // scales first: needed earliest (r,c are on the FMA-chain critical path)
        const float su0 = sA[u0], sv0 = sB[v0];
        const float su1 = sA[u1], sv1 = sB[v1];
        const unsigned char* ra0 = Aq + (unsigned)u0 * 128;
        const unsigned char* rb0 = Bq + (unsigned)v0 * 128;
        const unsigned char* ra1 = Aq + (unsigned)u1 * 128;
        const unsigned char* rb1 = Bq + (unsigned)v1 * 128;
        uint4 A00 = *reinterpret_cast<const uint4*>(ra0 + k0a);
        uint4 A01 = *reinterpret_cast<const uint4*>(ra0 + k0b);
        uint4 B00 = *reinterpret_cast<const uint4*>(rb0 + k0a);
        uint4 B01 = *reinterpret_cast<const uint4*>(rb0 + k0b);
        uint4 A10 = *reinterpret_cast<const uint4*>(ra1 + k0a);
        uint4 A11 = *reinterpret_cast<const uint4*>(ra1 + k0b);
        uint4 B10 = *reinterpret_cast<const uint4*>(rb1 + k0a);
        uint4 B11 = *reinterpret_cast<const uint4*>(rb1 + k0b);

        {   // ---- edge e0
            const float r = sv0 * __builtin_amdgcn_rcpf(su0);   // su > 0 by construction
            const float c = fmaf(r, 128.0f, 128.0f);            // 128*(1+r)
            unsigned int aw[8] = {A00.x, A00.y, A00.z, A00.w, A01.x, A01.y, A01.z, A01.w};
            unsigned int bw[8] = {B00.x, B00.y, B00.z, B00.w, B01.x, B01.y, B01.z, B01.w};
            float p = 0.f;
#pragma unroll
            for (int wi = 0; wi < 8; ++wi) {
#pragma unroll
                for (int byt = 0; byt < 4; ++byt) {
                    float fa = (float)((aw[wi] >> (8 * byt)) & 0xffu);  // v_cvt_f32_ubyteN
                    float fb = (float)((bw[wi] >> (8 * byt)) & 0xffu);
                    float s = fmaxf(fmaf(fb, r, fa) - c, 0.f);
                    p = fmaf(s, w2f[wi * 4 + byt], p);
                }
            }
            p += __shfl_xor(p, 1);
            p += __shfl_xor(p, 2);
            if (sl == 0) out[e0] = fmaf(su0, p, bias2);
        }
        {   // ---- edge e1
            const float r = sv1 * __builtin_amdgcn_rcpf(su1);
            const float c = fmaf(r, 128.0f, 128.0f);
            unsigned int aw[8] = {A10.x, A10.y, A10.z, A10.w, A11.x, A11.y, A11.z, A11.w};
            unsigned int bw[8] = {B10.x, B10.y, B10.z, B10.w, B11.x, B11.y, B11.z, B11.w};
            float p = 0.f;
#pragma unroll
            for (int wi = 0; wi < 8; ++wi) {
#pragma unroll
                for (int byt = 0; byt < 4; ++byt) {
                    float fa = (float)((aw[wi] >> (8 * byt)) & 0xffu);
                    float fb = (float)((bw[wi] >> (8 * byt)) & 0xffu);
                    float s = fmaxf(fmaf(fb, r, fa) - c, 0.f);
                    p = fmaf(s, w2f[wi * 4 + byt], p);
                }
            }
            p += __shfl_xor(p, 1);
            p += __shfl_xor(p, 2);
            if (sl == 0) out[e1] = fmaf(su1, p, bias2);
        }
    }
}

__global__ __launch_bounds__(256, 4) void edge_kernel(
    const long long* __restrict__ ei, const unsigned char* __restrict__ Aq,
    const unsigned char* __restrict__ Bq, const float* __restrict__ sA,
    const float* __restrict__ sB, const float* __restrict__ W2,
    const float* __restrict__ b2, float* __restrict__ out) {
    const int lane = threadIdx.x & 63;
    const int eg = lane >> 2;     // edge group 0..15 within wave
    const int sl = lane & 3;      // sub-lane within edge
    const float bias2 = b2[0];

    // int64-vs-int32 edge_index robustness probe (values < 1e5 -> hi words 0)
    const unsigned int hi = reinterpret_cast<const unsigned int*>(ei)[2 * lane + 1];
    const bool is64 = (__ballot(hi != 0) == 0ull);

    const int wid = (int)(((unsigned)(blockIdx.x * blockDim.x + threadIdx.x)) >> 6);
    const int nwaves = (int)(((unsigned)(gridDim.x * blockDim.x)) >> 6);

    if (is64) edge_loop<true>(ei, Aq, Bq, sA, sB, W2, bias2, out, wid, nwaves, eg, sl);
    else      edge_loop<false>(ei, Aq, Bq, sA, sB, W2, bias2, out, wid, nwaves, eg, sl);
}

extern "C" void kernel_launch(void* const* d_in, const int* in_sizes, int n_in,
                              void* d_out, int out_size, void* d_ws, size_t ws_size,
                              hipStream_t stream) {
    const float* x = (const float*)d_in[0];
    const long long* ei = (const long long*)d_in[1];
    const float* W1 = (const float*)d_in[2];
    const float* b1 = (const float*)d_in[3];
    const float* W2 = (const float*)d_in[4];
    const float* b2 = (const float*)d_in[5];
    float* out = (float*)d_out;

    unsigned char* Aq = (unsigned char*)d_ws;
    unsigned char* Bq = (unsigned char*)d_ws + BQ_OFF;
    float* sA = (float*)((char*)d_ws + SA_OFF);
    float* sB = (float*)((char*)d_ws + SB_OFF);

    dim3 g1(PRE_BLKX, 2);
    precompute_kernel<<<g1, 256, 0, stream>>>(x, W1, b1, Aq, Bq, sA, sB);
    edge_kernel<<<2048, 256, 0, stream>>>(ei, Aq, Bq, sA, sB, W2, b2, out);
}